// Round 1
// baseline (647.703 us; speedup 1.0000x reference)
//
#include <hip/hip_runtime.h>

#define NB   8
#define BKK  288
#define CWW  1152
#define HH   17
#define EPSF 1e-10f

// params layout per (b,j): [0..15]=mu, [16..31]=1/(2*sigsq), [32..47]=a*0.39894/(sig+eps)

__global__ __launch_bounds__(256) void mstep_kernel(
    const float* __restrict__ votes,
    const float* __restrict__ rt_in,     // null => iter0: rt = a_/32
    const float* __restrict__ beta_v,
    const float* __restrict__ beta_a,
    float* __restrict__ params,          // non-final iters
    float* __restrict__ out_mua)         // final iter (params == null)
{
    const int wid  = (blockIdx.x * 256 + threadIdx.x) >> 6;   // 0..9215 = b*1152+j
    const int lane = threadIdx.x & 63;
    const int h    = lane & 15;
    const int isub = lane >> 4;          // 0..3
    const int b = wid / CWW;
    const int j = wid - b * CWW;

    const float* vb = votes + ((size_t)b * BKK * CWW + j) * HH;
    float s0 = 0.f, s1 = 0.f, s2 = 0.f;
    if (rt_in) {
        const float* rb = rt_in + (size_t)b * BKK * CWW + j;
        for (int i = isub; i < BKK; i += 4) {
            float v  = vb[(size_t)i * CWW * HH + h];
            float rt = rb[(size_t)i * CWW];
            s0 += rt; s1 += rt * v; s2 += rt * v * v;
        }
    } else {
        for (int i = isub; i < BKK; i += 4) {
            const float* rec = vb + (size_t)i * CWW * HH;
            float v  = rec[h];
            float rt = rec[16] * (1.f / 32.f);
            s0 += rt; s1 += rt * v; s2 += rt * v * v;
        }
    }
    // reduce across the 4 isub groups (lane xor 16, 32)
    s0 += __shfl_xor(s0, 16); s1 += __shfl_xor(s1, 16); s2 += __shfl_xor(s2, 16);
    s0 += __shfl_xor(s0, 32); s1 += __shfl_xor(s1, 32); s2 += __shfl_xor(s2, 32);

    float sumR  = s0 + 1e-4f;
    float mu    = s1 / sumR;
    float var   = s2 - 2.f * mu * s1 + mu * mu * s0 + EPSF * s0; // = sum Rt*((V-mu)^2+EPS)
    var = fmaxf(var, 0.f);
    float sigsq = var / sumR + EPSF;
    float sig   = sqrtf(sigsq);
    float ls    = logf(sig + EPSF);
    // sum over the 16 h lanes (xor 1,2,4,8 stays within the isub group)
    float lssum = ls;
    lssum += __shfl_xor(lssum, 1);
    lssum += __shfl_xor(lssum, 2);
    lssum += __shfl_xor(lssum, 4);
    lssum += __shfl_xor(lssum, 8);
    const int c = j / 36;
    float cost = (16.f * beta_v[c] + lssum) * sumR;
    float aa   = 1.f / (1.f + expf(-1e-4f * (beta_a[c] - cost)));

    if (params) {
        if (isub == 0) {
            float* p = params + (size_t)(b * CWW + j) * 48;
            p[h]      = mu;
            p[16 + h] = 0.5f / sigsq;
            p[32 + h] = aa * 0.3989422804014327f / (sig + EPSF);
        }
    } else {
        float* o = out_mua + (size_t)(b * CWW + j) * HH;
        if (isub == 0) o[h] = mu;
        if (lane == 16) o[16] = aa;   // a into last slot
    }
}

__global__ __launch_bounds__(256) void estep_kernel(
    const float* __restrict__ votes,
    const float* __restrict__ params,
    float* __restrict__ rt_out)          // Rt = (ap/(sum+eps)+eps)*a_
{
    __shared__ float apsh[CWW];
    __shared__ float wred[4];
    const int bi  = blockIdx.x;          // b*288+i
    const int b   = bi / BKK;
    const int tid = threadIdx.x;
    const float* base = votes + (size_t)bi * CWW * HH;

    float psum = 0.f;
    for (int j = tid; j < CWW; j += 256) {
        const float* rec = base + j * HH;
        const float4* p4 = (const float4*)(params + (size_t)(b * CWW + j) * 48);
        float pm[16], pi[16], pw[16];
        ((float4*)pm)[0] = p4[0]; ((float4*)pm)[1] = p4[1];
        ((float4*)pm)[2] = p4[2]; ((float4*)pm)[3] = p4[3];
        ((float4*)pi)[0] = p4[4]; ((float4*)pi)[1] = p4[5];
        ((float4*)pi)[2] = p4[6]; ((float4*)pi)[3] = p4[7];
        ((float4*)pw)[0] = p4[8]; ((float4*)pw)[1] = p4[9];
        ((float4*)pw)[2] = p4[10]; ((float4*)pw)[3] = p4[11];
        float pj = 0.f;
        #pragma unroll
        for (int k = 0; k < 16; k++) {
            float d  = rec[k] - pm[k];
            float d2 = d * d + EPSF;
            pj += pw[k] * __expf(-d2 * pi[k]);
        }
        apsh[j] = pj;
        psum += pj;
    }
    // block reduce psum
    for (int off = 32; off > 0; off >>= 1) psum += __shfl_down(psum, off);
    if ((tid & 63) == 0) wred[tid >> 6] = psum;
    __syncthreads();
    float apsum = wred[0] + wred[1] + wred[2] + wred[3];
    float inv = 1.f / (apsum + EPSF);
    for (int j = tid; j < CWW; j += 256) {
        float rw = apsh[j] * inv + EPSF;
        rt_out[(size_t)bi * CWW + j] = rw * base[j * HH + 16];
    }
}

__global__ __launch_bounds__(256) void copy4_kernel(
    const float4* __restrict__ src, float4* __restrict__ dst, int n)
{
    int idx = blockIdx.x * 256 + threadIdx.x;
    if (idx < n) dst[idx] = src[idx];
}

extern "C" void kernel_launch(void* const* d_in, const int* in_sizes, int n_in,
                              void* d_out, int out_size, void* d_ws, size_t ws_size,
                              hipStream_t stream)
{
    const float* votes  = (const float*)d_in[0];
    const float* beta_v = (const float*)d_in[1];
    const float* beta_a = (const float*)d_in[2];
    float* out       = (float*)d_out;
    float* out_mua   = out;                                  // 8*1152*17 = 156672
    float* out_R     = out + (size_t)NB * CWW * HH;          // 8*288*1152 = 2654208
    float* out_votes = out_R + (size_t)NB * BKK * CWW;       // 45121536
    // params scratch lives in the votes output region; the final copy
    // (stream-ordered, launched last) overwrites it.
    float* params = out_votes;

    dim3 blk(256);
    dim3 gm(NB * CWW / 4);   // 2304 blocks, 1 wave per (b,j)
    dim3 ge(NB * BKK);       // 2304 blocks, 1 block per (b,i)

    // iter 0
    mstep_kernel<<<gm, blk, 0, stream>>>(votes, nullptr, beta_v, beta_a, params, nullptr);
    estep_kernel<<<ge, blk, 0, stream>>>(votes, params, out_R);
    // iter 1
    mstep_kernel<<<gm, blk, 0, stream>>>(votes, out_R, beta_v, beta_a, params, nullptr);
    estep_kernel<<<ge, blk, 0, stream>>>(votes, params, out_R);   // writes final R_out
    // iter 2 (final): mu/a -> out_mua
    mstep_kernel<<<gm, blk, 0, stream>>>(votes, out_R, beta_v, beta_a, nullptr, out_mua);
    // votes passthrough (overwrites params scratch)
    int n4 = (int)((size_t)NB * BKK * CWW * HH / 4);
    copy4_kernel<<<dim3((n4 + 255) / 256), blk, 0, stream>>>(
        (const float4*)votes, (float4*)out_votes, n4);
}

// Round 2
// 532.790 us; speedup vs baseline: 1.2157x; 1.2157x over previous
//
#include <hip/hip_runtime.h>

#define NB   8
#define BKK  288
#define CWW  1152
#define HH   17
#define EPSF 1e-10f
#define ICH  8            // i-chunks for mstep partials
#define ISZ  (BKK/ICH)    // 36 i per chunk
#define JT   (CWW/64)     // 18 j-tiles of 64

// params layout per (b,j): [0..15]=mu, [16..31]=1/(2*sigsq), [32..47]=a*rsqrt(2pi)/(sig+eps)
// p12 layout per (b,j,chunk): [0..15]=s1[h], [16..31]=s2[h]
// p0  layout per (b,j,chunk): s0

__global__ __launch_bounds__(256) void mpart_kernel(
    const float* __restrict__ votes,
    const float* __restrict__ rt_in,     // null => iter0: rt = a_/32
    float* __restrict__ p12,
    float* __restrict__ p0)
{
    const int jb = blockIdx.x;           // 0..NB*JT-1
    const int c  = blockIdx.y;           // chunk 0..7
    const int b  = jb / JT;
    const int j  = (jb - b * JT) * 64 + (threadIdx.x >> 2);
    const int h4 = threadIdx.x & 3;

    const size_t rowstride = (size_t)CWW * HH;
    const float* vrec = votes + ((size_t)(b * BKK + c * ISZ) * CWW + j) * HH;

    float s0 = 0.f;
    float s1[4] = {0.f, 0.f, 0.f, 0.f};
    float s2[4] = {0.f, 0.f, 0.f, 0.f};

    if (rt_in) {
        const float* rb = rt_in + (size_t)(b * BKK + c * ISZ) * CWW + j;
        for (int i = 0; i < ISZ; i++) {
            float rt = rb[(size_t)i * CWW];
            const float* rec = vrec + (size_t)i * rowstride;
            #pragma unroll
            for (int k = 0; k < 4; k++) {
                float v = rec[h4 * 4 + k];
                s1[k] += rt * v;
                s2[k] += rt * v * v;
            }
            s0 += rt;
        }
    } else {
        for (int i = 0; i < ISZ; i++) {
            const float* rec = vrec + (size_t)i * rowstride;
            float rt = rec[16] * (1.f / 32.f);
            #pragma unroll
            for (int k = 0; k < 4; k++) {
                float v = rec[h4 * 4 + k];
                s1[k] += rt * v;
                s2[k] += rt * v * v;
            }
            s0 += rt;
        }
    }

    float* o = p12 + (((size_t)(b * CWW + j)) * ICH + c) * 32 + h4 * 4;
    *(float4*)o        = make_float4(s1[0], s1[1], s1[2], s1[3]);
    *(float4*)(o + 16) = make_float4(s2[0], s2[1], s2[2], s2[3]);
    if (h4 == 0) p0[((size_t)(b * CWW + j)) * ICH + c] = s0;
}

__global__ __launch_bounds__(256) void mfin_kernel(
    const float* __restrict__ p12,
    const float* __restrict__ p0,
    const float* __restrict__ beta_v,
    const float* __restrict__ beta_a,
    float* __restrict__ params,          // non-final iters
    float* __restrict__ out_mua)         // final iter (params == null)
{
    const int wid  = (blockIdx.x * 256 + threadIdx.x) >> 6;   // bj = b*1152+j
    const int lane = threadIdx.x & 63;
    const int h    = lane & 15;
    const int q    = lane >> 4;
    const int b    = wid / CWW;
    const int j    = wid - b * CWW;

    float s0 = 0.f, s1 = 0.f, s2 = 0.f;
    #pragma unroll
    for (int cc = 0; cc < 2; cc++) {
        int c = q + cc * 4;
        const float* pp = p12 + ((size_t)wid * ICH + c) * 32;
        s1 += pp[h];
        s2 += pp[16 + h];
        s0 += p0[(size_t)wid * ICH + c];
    }
    s0 += __shfl_xor(s0, 16); s1 += __shfl_xor(s1, 16); s2 += __shfl_xor(s2, 16);
    s0 += __shfl_xor(s0, 32); s1 += __shfl_xor(s1, 32); s2 += __shfl_xor(s2, 32);

    float sumR  = s0 + 1e-4f;
    float mu    = s1 / sumR;
    float var   = s2 - 2.f * mu * s1 + mu * mu * s0 + EPSF * s0;
    var = fmaxf(var, 0.f);
    float sigsq = var / sumR + EPSF;
    float sig   = sqrtf(sigsq);
    float ls    = logf(sig + EPSF);
    float lssum = ls;
    lssum += __shfl_xor(lssum, 1);
    lssum += __shfl_xor(lssum, 2);
    lssum += __shfl_xor(lssum, 4);
    lssum += __shfl_xor(lssum, 8);
    const int c = j / 36;
    float cost = (16.f * beta_v[c] + lssum) * sumR;
    float aa   = 1.f / (1.f + expf(-1e-4f * (beta_a[c] - cost)));

    if (params) {
        if (q == 0) {
            float* p = params + (size_t)wid * 48;
            p[h]      = mu;
            p[16 + h] = 0.5f / sigsq;
            p[32 + h] = aa * 0.3989422804014327f / (sig + EPSF);
        }
    } else {
        float* o = out_mua + (size_t)wid * HH;
        if (q == 0) o[h] = mu;
        if (lane == 16) o[16] = aa;
    }
}

__global__ __launch_bounds__(256) void estep_kernel(
    const float* __restrict__ votes,
    const float* __restrict__ params,
    float* __restrict__ rt_out,          // Rt = (ap/(sum+eps)+eps)*a_
    float* __restrict__ copy_dst)        // non-null: also copy votes row to out
{
    __shared__ float apsh[CWW];
    __shared__ float wred[4];
    const int bi = blockIdx.x;           // b*288+i
    const int b  = bi / BKK;
    const int t  = threadIdx.x;
    const int jl = t >> 2;
    const int h4 = t & 3;
    const float* base = votes + (size_t)bi * CWW * HH;
    const float* pb   = params + (size_t)b * CWW * 48;

    float psum = 0.f;
    for (int tile = 0; tile < JT; tile++) {
        int j = tile * 64 + jl;
        const float* rec = base + j * HH + h4 * 4;
        const float* pj4 = pb + (size_t)j * 48 + h4 * 4;
        float4 pm = *(const float4*)(pj4);
        float4 pi = *(const float4*)(pj4 + 16);
        float4 pw = *(const float4*)(pj4 + 32);
        float v0 = rec[0], v1 = rec[1], v2 = rec[2], v3 = rec[3];
        float d, pj = 0.f;
        d = v0 - pm.x; pj += pw.x * __expf(-(d * d + EPSF) * pi.x);
        d = v1 - pm.y; pj += pw.y * __expf(-(d * d + EPSF) * pi.y);
        d = v2 - pm.z; pj += pw.z * __expf(-(d * d + EPSF) * pi.z);
        d = v3 - pm.w; pj += pw.w * __expf(-(d * d + EPSF) * pi.w);
        pj += __shfl_xor(pj, 1);
        pj += __shfl_xor(pj, 2);
        if (h4 == 0) {
            apsh[j] = pj;
            psum += pj;
        }
    }
    for (int off = 32; off > 0; off >>= 1) psum += __shfl_down(psum, off);
    if ((t & 63) == 0) wred[t >> 6] = psum;
    __syncthreads();
    float inv = 1.f / ((wred[0] + wred[1] + wred[2] + wred[3]) + EPSF);

    for (int j = t; j < CWW; j += 256) {
        rt_out[(size_t)bi * CWW + j] = (apsh[j] * inv + EPSF) * base[j * HH + 16];
    }

    if (copy_dst) {
        const float4* s4 = (const float4*)base;
        float4* d4 = (float4*)(copy_dst + (size_t)bi * CWW * HH);
        for (int idx = t; idx < (CWW * HH) / 4; idx += 256) d4[idx] = s4[idx];
    }
}

__global__ __launch_bounds__(256) void copy4_kernel(
    const float4* __restrict__ src, float4* __restrict__ dst, int n)
{
    int idx = blockIdx.x * 256 + threadIdx.x;
    if (idx < n) dst[idx] = src[idx];
}

extern "C" void kernel_launch(void* const* d_in, const int* in_sizes, int n_in,
                              void* d_out, int out_size, void* d_ws, size_t ws_size,
                              hipStream_t stream)
{
    const float* votes  = (const float*)d_in[0];
    const float* beta_v = (const float*)d_in[1];
    const float* beta_a = (const float*)d_in[2];
    float* out       = (float*)d_out;
    float* out_mua   = out;                                  // 8*1152*17 = 156672
    float* out_R     = out + (size_t)NB * CWW * HH;          // 8*288*1152 = 2654208
    float* out_votes = out_R + (size_t)NB * BKK * CWW;       // 45121536

    const size_t n_params = (size_t)NB * CWW * 48;           //   442368
    const size_t n_p12    = (size_t)NB * CWW * ICH * 32;     //  2359296
    const size_t n_p0     = (size_t)NB * CWW * ICH;          //    73728
    const size_t need     = (n_params + n_p12 + n_p0) * sizeof(float);

    float *params, *p12, *p0;
    bool fused;
    if (ws_size >= need) {
        params = (float*)d_ws;
        fused  = true;
    } else {
        // fallback: scratch lives in the votes output region; final copy
        // kernel (launched last) overwrites it.
        params = out_votes;
        fused  = false;
    }
    p12 = params + n_params;
    p0  = p12 + n_p12;

    dim3 blk(256);
    dim3 gmp(NB * JT, ICH);  // 144 x 8
    dim3 gmf(NB * CWW / 4);  // 2304 (4 waves/block, wave per (b,j))
    dim3 ge(NB * BKK);       // 2304 (block per (b,i))

    // iter 0
    mpart_kernel<<<gmp, blk, 0, stream>>>(votes, nullptr, p12, p0);
    mfin_kernel<<<gmf, blk, 0, stream>>>(p12, p0, beta_v, beta_a, params, nullptr);
    estep_kernel<<<ge, blk, 0, stream>>>(votes, params, out_R, nullptr);
    // iter 1
    mpart_kernel<<<gmp, blk, 0, stream>>>(votes, out_R, p12, p0);
    mfin_kernel<<<gmf, blk, 0, stream>>>(p12, p0, beta_v, beta_a, params, nullptr);
    estep_kernel<<<ge, blk, 0, stream>>>(votes, params, out_R,
                                         fused ? out_votes : nullptr);
    // iter 2 (final): mu/a -> out_mua
    mpart_kernel<<<gmp, blk, 0, stream>>>(votes, out_R, p12, p0);
    mfin_kernel<<<gmf, blk, 0, stream>>>(p12, p0, beta_v, beta_a, nullptr, out_mua);

    if (!fused) {
        int n4 = (int)((size_t)NB * BKK * CWW * HH / 4);
        copy4_kernel<<<dim3((n4 + 255) / 256), blk, 0, stream>>>(
            (const float4*)votes, (float4*)out_votes, n4);
    }
}